// Round 7
// baseline (469.047 us; speedup 1.0000x reference)
//
#include <hip/hip_runtime.h>

typedef unsigned short ushort_t;
typedef __attribute__((ext_vector_type(4))) float float4_t;
typedef __attribute__((ext_vector_type(8))) short short8_t;
typedef __attribute__((ext_vector_type(8))) unsigned short ushort8_t;
typedef __attribute__((ext_vector_type(4))) unsigned short ushort4_t;

// fp32 -> bf16 round-to-nearest-even (raw bits)
__device__ __forceinline__ ushort_t f2bf(float f) {
    unsigned u = __builtin_bit_cast(unsigned, f);
    u = (u + 0x7fffu + ((u >> 16) & 1u)) >> 16;
    return (ushort_t)u;
}
// fp32 <-> fp16
__device__ __forceinline__ ushort_t f2h(float f) {
    return __builtin_bit_cast(unsigned short, (_Float16)f);
}
__device__ __forceinline__ float h2f(ushort_t u) {
    return (float)__builtin_bit_cast(_Float16, u);
}

// async global->LDS, 16B per lane; lds dest is wave-uniform base (HW adds lane*16)
__device__ __forceinline__ void gld16(const void* g, void* l) {
    __builtin_amdgcn_global_load_lds(
        (const __attribute__((address_space(1))) unsigned int*)g,
        (__attribute__((address_space(3))) unsigned int*)l, 16, 0, 0);
}

// ---------------------------------------------------------------------------
// ws layout (bytes):
//   xn   [16][130][130][128] bf16  @ 0          NHWC + 1px zero halo
//   w2   [16][9][128][128]  bf16   @ 69222400   per-sample weights
//   p    [16][128] f32             @ 73940992   routing avgpool
//   cp   [16][128] f32             @ 73949184   SE channel sums (analytic)
//   cw   [16][128] f32             @ 73958400   SE sigmoid weights
//   sp   [16][2][134][134] f32     @ 73966592   spatial stats, 3px zero halo
//   outi [16][128][128][128] fp16  @ 76264960   conv result (intermediate)
//   st   [16][128][8] f32          @ 143373824  border stats per (b,i):
//        {row0,row127,col0,col127,x00,x0_127,x127_0,x127_127}
// ---------------------------------------------------------------------------

__global__ __launch_bounds__(256) void init_kernel(float* __restrict__ p, float* __restrict__ st,
                                                   float* __restrict__ sp, ushort_t* __restrict__ xn) {
    int t = blockIdx.x * 256 + threadIdx.x;
    if (t < 2048) { p[t] = 0.f; return; }
    if (t < 18432) { st[t - 2048] = 0.f; return; }          // 16*128*8
    if (t < 18432 + 574592) { sp[t - 18432] = 0.f; return; }
    int e = t - (18432 + 574592);
    if (e < 1056768) {                 // 16 * 516 * 128 halo elements
        int b = e / 66048;             // 516*128
        int r = e % 66048;
        int pix = r >> 7, i = r & 127;
        int hp, wp;
        if (pix < 130)      { hp = 0;   wp = pix; }
        else if (pix < 260) { hp = 129; wp = pix - 130; }
        else { int q = pix - 260; hp = 1 + (q >> 1); wp = (q & 1) ? 129 : 0; }
        xn[((b * 130 + hp) * 130 + wp) * 128 + i] = 0;
    }
}

// NCHW fp32 -> NHWC bf16 (haloed), fused routing avg-pool + border stats.
__global__ __launch_bounds__(256) void transpose_kernel(const float* __restrict__ x,
                                                        ushort_t* __restrict__ xn,
                                                        float* __restrict__ p,
                                                        float* __restrict__ st) {
    __shared__ float tile[128][65];
    int blk = blockIdx.x;
    int wt = blk & 1, h = (blk >> 1) & 127, b = blk >> 8;
    int w0 = wt * 64;
    int tid = threadIdx.x;
    int wl = tid & 63, ig = tid >> 6;
    const float* src = x + ((long)(b * 128) * 128 + h) * 128 + w0 + wl;  // x[b][i][h][w]
    #pragma unroll
    for (int i = ig; i < 128; i += 4) tile[i][wl] = src[(long)i * 16384];
    __syncthreads();
    if (tid < 128) {   // routing avgpool partials + border stats (fp32, pre-quant)
        float s = 0.f;
        #pragma unroll
        for (int w = 0; w < 64; ++w) s += tile[tid][w];
        atomicAdd(&p[b * 128 + tid], s * (1.0f / 16384.0f));
        float* sb = st + ((b << 7) + tid) * 8;
        if (h == 0)   atomicAdd(&sb[0], s);          // row0 partial
        if (h == 127) atomicAdd(&sb[1], s);          // row127 partial
        float edge = tile[tid][wt ? 63 : 0];         // x[b,i,h,0] or x[b,i,h,127]
        atomicAdd(&sb[wt ? 3 : 2], edge);            // col0 / col127 sums
        if (h == 0)   sb[wt ? 5 : 4] = edge;         // x00 / x0_127 (unique writer)
        if (h == 127) sb[wt ? 7 : 6] = edge;         // x127_0 / x127_127
    }
    int l16 = tid & 15, wq = tid >> 4;
    #pragma unroll
    for (int pass = 0; pass < 4; ++pass) {
        int w = wq + pass * 16;
        ushort8_t v;
        #pragma unroll
        for (int j = 0; j < 8; ++j) v[j] = f2bf(tile[l16 * 8 + j][w]);
        *(ushort8_t*)&xn[((b * 130 + h + 1) * 130 + (w0 + w + 1)) * 128 + l16 * 8] = v;
    }
}

// FUSED routing MLP + expert mix + ANALYTIC cp, single pass over experts.
// grid 128 (one block per o). cp[b][o] = sum_{i,d} w2fp32[b,d,o,i] * S[b,i,d]
// where S[d] are shifted-window sums of x built from T + border stats.
__global__ __launch_bounds__(256) void wgen_kernel(const float* __restrict__ experts,
        const float* __restrict__ p, const float* __restrict__ st,
        const float* __restrict__ rw1, const float* __restrict__ g1, const float* __restrict__ b1,
        const float* __restrict__ rw2, const float* __restrict__ g2, const float* __restrict__ b2,
        const float* __restrict__ rw3, const float* __restrict__ rb3,
        ushort_t* __restrict__ w2, float* __restrict__ cp) {
    int o = blockIdx.x;
    int tid = threadIdx.x;
    int lane = tid & 63, wave = tid >> 6;
    __shared__ __align__(16) float ex[16 * 1152];   // [e][i*9+d]
    __shared__ float sg[16][128];
    __shared__ float sh[16][16];
    __shared__ float sl[16][16];
    __shared__ float rwl[16][16];
    __shared__ float cpw[4][8];

    // 1) issue expert DMA (4608 B per e = 4.5 wave-segments)
    const float* ebase = experts + (long)o * 1152;
    #pragma unroll
    for (int j = 0; j < 4; ++j) {
        int e = wave * 4 + j;
        const char* src = (const char*)(ebase + (long)e * 147456) + lane * 16;
        char* dst = (char*)&ex[e * 1152];
        #pragma unroll
        for (int k = 0; k < 5; ++k) {
            if (k < 4 || lane < 32)
                gld16(src + k * 1024, dst + k * 1024);
        }
    }

    // 2) routing MLP (redundant per block; independent of ex)
    const float bns = rsqrtf(1.0f + 1e-5f);
    {   int b = tid >> 4, j = tid & 15;
        float s = 0.f;
        for (int i = 0; i < 128; ++i) s += p[b * 128 + i] * rw1[j * 128 + i];
        s = s * (g1[j] * bns) + b1[j];
        sh[b][j] = fmaxf(s, 0.f); }
    __syncthreads();
    for (int c = 0; c < 8; ++c) {
        int idx = tid + c * 256;
        int b = idx >> 7, j = idx & 127;
        float s = 0.f;
        for (int k = 0; k < 16; ++k) s += sh[b][k] * rw2[j * 16 + k];
        s = s * (g2[j] * bns) + b2[j];
        sg[b][j] = 1.0f / (1.0f + expf(-s));
    }
    __syncthreads();
    {   int b = tid >> 4, e = tid & 15;
        float s = rb3[e];
        for (int j = 0; j < 128; ++j) s += sg[b][j] * rw3[e * 128 + j];
        sl[b][e] = s; }
    __syncthreads();
    {   int b = tid >> 4, e = tid & 15;
        float m = -1e30f;
        for (int k = 0; k < 16; ++k) m = fmaxf(m, sl[b][k]);
        float num = expf(sl[b][e] - m), den = 0.f;
        for (int k = 0; k < 16; ++k) den += expf(sl[b][k] - m);
        rwl[b][e] = num / den; }
    asm volatile("s_waitcnt vmcnt(0)" ::: "memory");
    __syncthreads();

    // 3) mix (fp32) + analytic cp contraction; each half does 8 b's
    int i = tid & 127, half = tid >> 7;
    float acc[8][9];
    #pragma unroll
    for (int b = 0; b < 8; ++b)
        #pragma unroll
        for (int d = 0; d < 9; ++d) acc[b][d] = 0.f;
    for (int e = 0; e < 16; ++e) {
        float v[9];
        #pragma unroll
        for (int d = 0; d < 9; ++d) v[d] = ex[e * 1152 + i * 9 + d];
        #pragma unroll
        for (int b = 0; b < 8; ++b) {
            float r = rwl[half * 8 + b][e];
            #pragma unroll
            for (int d = 0; d < 9; ++d) acc[b][d] += v[d] * r;
        }
    }
    float cps[8];
    #pragma unroll
    for (int bb2 = 0; bb2 < 8; ++bb2) {
        int b = half * 8 + bb2;
        const float* sb = st + ((b << 7) + i) * 8;
        float T = p[(b << 7) + i] * 16384.f;
        float r0 = sb[0], r127 = sb[1], c0 = sb[2], c127 = sb[3];
        float x00 = sb[4], x0127 = sb[5], x1270 = sb[6], x127127 = sb[7];
        // S[d], d = ky*3+kx: window sums of x shifted by (ky-1, kx-1)
        float S0 = T - r127 - c127 + x127127;
        float S1 = T - r127;
        float S2 = T - r127 - c0 + x1270;
        float S3 = T - c127;
        float S4 = T;
        float S5 = T - c0;
        float S6 = T - r0 - c127 + x0127;
        float S7 = T - r0;
        float S8 = T - r0 - c0 + x00;
        cps[bb2] = acc[bb2][0] * S0 + acc[bb2][1] * S1 + acc[bb2][2] * S2 +
                   acc[bb2][3] * S3 + acc[bb2][4] * S4 + acc[bb2][5] * S5 +
                   acc[bb2][6] * S6 + acc[bb2][7] * S7 + acc[bb2][8] * S8;
    }
    // reduce over the 64 i-lanes of this wave
    #pragma unroll
    for (int bb2 = 0; bb2 < 8; ++bb2)
        for (int msk = 1; msk < 64; msk <<= 1) cps[bb2] += __shfl_xor(cps[bb2], msk, 64);
    if (lane == 0) {
        #pragma unroll
        for (int bb2 = 0; bb2 < 8; ++bb2) cpw[wave][bb2] = cps[bb2];
    }
    #pragma unroll
    for (int b = 0; b < 8; ++b)
        #pragma unroll
        for (int d = 0; d < 9; ++d)
            w2[(((half * 8 + b) * 9 + d) << 14) + (o << 7) + i] = f2bf(acc[b][d]);
    __syncthreads();
    if (tid < 16) {
        int hf = tid >> 3, idx = tid & 7;
        cp[(tid << 7) + o] = cpw[hf * 2][idx] + cpw[hf * 2 + 1][idx];
    }
}

// tiny SE MLP: cp -> cw (1 block)
__global__ __launch_bounds__(256) void se_kernel(const float* __restrict__ cp,
        const float* __restrict__ w1, const float* __restrict__ g1, const float* __restrict__ b1,
        const float* __restrict__ w2, const float* __restrict__ g2, const float* __restrict__ b2,
        float* __restrict__ cw) {
    __shared__ float sc[16][128];
    __shared__ float sh[16][16];
    int tid = threadIdx.x;
    const float bns = rsqrtf(1.0f + 1e-5f);
    for (int c = 0; c < 8; ++c) {
        int idx = tid + c * 256;
        sc[idx >> 7][idx & 127] = cp[idx] * (1.0f / 16384.0f);
    }
    __syncthreads();
    {   int b = tid >> 4, j = tid & 15;
        float s = 0.f;
        for (int o = 0; o < 128; ++o) s += sc[b][o] * w1[j * 128 + o];
        s = s * (g1[j] * bns) + b1[j];
        sh[b][j] = fmaxf(s, 0.f); }
    __syncthreads();
    for (int c = 0; c < 8; ++c) {
        int idx = tid + c * 256;
        int b = idx >> 7, o = idx & 127;
        float s = 0.f;
        for (int k = 0; k < 16; ++k) s += sh[b][k] * w2[o * 16 + k];
        s = s * (g2[o] * bns) + b2[o];
        cw[idx] = 1.0f / (1.0f + expf(-s));
    }
}

// Per-sample conv as MFMA implicit GEMM (round-3 schedule) + FUSED spatial
// stats: epilogue computes channel-weighted mean/max (cw loaded in prologue)
// from the staged fp32 slices and writes sp directly -- stat_kernel deleted.
struct __align__(16) ConvSmem {
    union {
        struct { ushort_t X[16640]; ushort_t A[4][4096]; } t;
        float c[4224];   // epilogue staging: 32 rows x 132 (padded) fp32
    };
};

__global__ __launch_bounds__(256, 2) void conv_kernel(const ushort_t* __restrict__ xn,
                                                      const ushort_t* __restrict__ w2,
                                                      const float* __restrict__ cw,
                                                      ushort_t* __restrict__ outi,
                                                      float* __restrict__ sp) {
    __shared__ ConvSmem sm;
    __shared__ float scw[128];
    __shared__ float cmb[2][128];
    // XCD-aware swizzle (2048 % 8 == 0 -> bijective)
    int bh = (blockIdx.x & 7) * 256 + (blockIdx.x >> 3);
    int b = bh >> 7, h = bh & 127;
    int tid = threadIdx.x;
    int lane = tid & 63, wave = tid >> 6;
    int wm = wave & 1, wn = wave >> 1;
    int q = lane >> 4, nl = lane & 15;

    float4_t acc[4][4];
    #pragma unroll
    for (int mi = 0; mi < 4; ++mi)
        #pragma unroll
        for (int ni = 0; ni < 4; ++ni) acc[mi][ni] = (float4_t){0.f, 0.f, 0.f, 0.f};

    const ushort_t* xbase = xn + (b * 130 + h) * 16640;
    const ushort_t* abase = w2 + (long)b * 147456;

    // cw load FIRST (oldest vmem op -> its wait leaves the DMAs in flight)
    float cwv = 0.f;
    if (tid < 128) cwv = cw[(b << 7) + tid];

    auto stageX = [&](int dy) {
        const ushort_t* xrow = xbase + dy * 16640;
        #pragma unroll
        for (int seg = wave; seg < 33; seg += 4) {
            if (seg < 32 || lane < 32) {
                int lofs = seg * 512 + lane * 8;
                int pp = lofs >> 7;
                int jb = (lofs & 127) >> 3;
                gld16(xrow + (pp << 7) + ((jb ^ (pp & 15)) << 3), &sm.t.X[seg * 512]);
            }
        }
    };
    auto stageA = [&](int c) {   // c = chunk 0..35; exactly 2 gld16 per wave
        int dy = c / 12, rem = c % 12, dx = rem >> 2, ic = rem & 3;
        const ushort_t* ab = abase + (dy * 3 + dx) * 16384 + ic * 32;
        int buf = c & 3;
        int ol = lane >> 2;
        int jsrc = (lane & 3) ^ ((ol >> 1) & 3);   // bank-spread swizzle: f(o) = (o>>1)&3
        #pragma unroll
        for (int inst = 0; inst < 2; ++inst) {
            int ob = wave * 32 + inst * 16;
            gld16(ab + (ob + ol) * 128 + (jsrc << 3), &sm.t.A[buf][ob * 32]);
        }
    };

    short8_t afr[2][4], bfr[2][4];
    auto readFrag = [&](int cc) {            // parity pb = cc & 1
        int pb = cc & 1;
        int dx = (cc % 12) >> 2, ic = cc & 3;
        const ushort_t* ap = &sm.t.A[cc & 3][0];
        #pragma unroll
        for (int mi = 0; mi < 4; ++mi) {
            int o = wm * 64 + mi * 16 + nl;
            afr[pb][mi] = *(const short8_t*)&ap[(o << 5) + ((q ^ ((o >> 1) & 3)) << 3)];
        }
        #pragma unroll
        for (int ni = 0; ni < 4; ++ni) {
            int pp = wn * 64 + ni * 16 + nl + dx;
            int J = ic * 4 + q;
            bfr[pb][ni] = *(const short8_t*)&sm.t.X[(pp << 7) + ((J ^ (pp & 15)) << 3)];
        }
    };
    auto domfma = [&](int pb) {
        __builtin_amdgcn_s_setprio(1);
        #pragma unroll
        for (int mi = 0; mi < 4; ++mi)
            #pragma unroll
            for (int ni = 0; ni < 4; ++ni)
                acc[mi][ni] = __builtin_amdgcn_mfma_f32_16x16x32_bf16(
                    afr[pb][mi], bfr[pb][ni], acc[mi][ni], 0, 0, 0);
        __builtin_amdgcn_s_setprio(0);
    };

    // prologue: X row 0 + A chunks 0..2, one full drain
    stageX(0);
    stageA(0); stageA(1); stageA(2);
    if (tid < 128) scw[tid] = cwv;   // visible by epilogue (many barriers later)
    asm volatile("s_waitcnt vmcnt(0)" ::: "memory");
    __builtin_amdgcn_s_barrier();
    readFrag(0);

    #pragma unroll
    for (int c = 0; c < 36; ++c) {
        if (c + 3 < 36) stageA(c + 3);
        const bool bnd = (c == 11 || c == 23);
        if (!bnd && c + 1 < 36) readFrag(c + 1);   // overlaps with MFMAs below
        domfma(c & 1);
        if (bnd) {
            // dy boundary: restage X, full drain (stageX counts are uneven)
            __builtin_amdgcn_s_barrier();
            stageX(c == 11 ? 1 : 2);
            asm volatile("s_waitcnt vmcnt(0)" ::: "memory");
            __builtin_amdgcn_s_barrier();
            readFrag(c + 1);
        } else if (c < 35) {
            // guarantee A(c+2) complete (read as frag at next chunk's start)
            if (c == 33)
                asm volatile("s_waitcnt vmcnt(0)" ::: "memory");
            else if (!(c == 0 || c == 12 || c == 24 || c == 34))
                asm volatile("s_waitcnt vmcnt(2)" ::: "memory");
            __builtin_amdgcn_s_barrier();
        }
    }

    // Epilogue: per-slice fp16 store + channel-weighted mean/max accumulation.
    ushort_t* outb = outi + (((long)(b << 7)) << 14) + (h << 7);
    int wpx = tid & 127, g = tid >> 7;
    float wsum = 0.f, wmax = -1e30f;
    #pragma unroll
    for (int os = 0; os < 4; ++os) {
        __syncthreads();   // previous slice readers / K-loop LDS readers done
        if (wm == (os >> 1)) {
            #pragma unroll
            for (int mi2 = 0; mi2 < 2; ++mi2) {
                int mi = (os & 1) * 2 + mi2;
                #pragma unroll
                for (int ni = 0; ni < 4; ++ni) {
                    float4_t v = acc[mi][ni];
                    int orow = mi2 * 16 + q * 4;
                    int w = wn * 64 + ni * 16 + nl;
                    #pragma unroll
                    for (int rr = 0; rr < 4; ++rr) sm.c[(orow + rr) * 132 + w] = v[rr];
                }
            }
        }
        __syncthreads();
        int row = tid >> 4, j = tid & 15;
        #pragma unroll
        for (int pass = 0; pass < 2; ++pass) {
            int r2 = pass * 16 + row;
            ushort8_t v;
            #pragma unroll
            for (int k = 0; k < 8; ++k) v[k] = f2h(sm.c[r2 * 132 + j * 8 + k]);
            *(ushort8_t*)&outb[((long)(os * 32 + r2) << 14) + j * 8] = v;
        }
        // weighted mean/max over this slice's 32 o's: thread (wpx, g) takes 16
        #pragma unroll
        for (int r = 0; r < 16; ++r) {
            int orow = g * 16 + r;
            float v = sm.c[orow * 132 + wpx] * scw[os * 32 + orow];
            wsum += v;
            wmax = fmaxf(wmax, v);
        }
    }
    if (g == 1) { cmb[0][wpx] = wsum; cmb[1][wpx] = wmax; }
    __syncthreads();
    if (g == 0) {
        wsum += cmb[0][wpx];
        wmax = fmaxf(wmax, cmb[1][wpx]);
        float* d = sp + b * 2 * 17956;
        d[(h + 3) * 134 + (wpx + 3)] = wsum * (1.0f / 128.0f);
        d[17956 + (h + 3) * 134 + (wpx + 3)] = wmax;
    }
}

// FUSED: 7x7 spatial-attention conv (2->1 ch) + bn + sigmoid, then apply
// out = fp16(conv)*cw*sw + x in fp32. Only writer of d_out.
__global__ __launch_bounds__(256) void sattn_kernel(const float* __restrict__ sp,
        const float* __restrict__ k98, const float* __restrict__ g, const float* __restrict__ bb,
        const float* __restrict__ cw, const float* __restrict__ x,
        const ushort_t* __restrict__ outi, float* __restrict__ out) {
    int b = blockIdx.x >> 7, h = blockIdx.x & 127;
    int tid = threadIdx.x;
    __shared__ float ls[2][7][134];
    __shared__ float lk[98];
    __shared__ float sws[128];
    __shared__ float scw[128];
    const float* sb = sp + b * 2 * 17956;
    for (int idx = tid; idx < 2 * 7 * 134; idx += 256) {
        int c = idx / 938, rr = idx % 938;
        int ky = rr / 134, wp = rr % 134;
        ls[c][ky][wp] = sb[c * 17956 + (h + ky) * 134 + wp];
    }
    if (tid < 98) lk[tid] = k98[tid];
    if (tid >= 128) scw[tid - 128] = cw[(b << 7) + (tid - 128)];
    __syncthreads();
    if (tid < 128) {
        float s = 0.f;
        #pragma unroll
        for (int c = 0; c < 2; ++c)
            #pragma unroll
            for (int ky = 0; ky < 7; ++ky)
                #pragma unroll
                for (int kx = 0; kx < 7; ++kx)
                    s += ls[c][ky][tid + kx] * lk[c * 49 + ky * 7 + kx];
        s = s * (g[0] * rsqrtf(1.0f + 1e-5f)) + bb[0];
        sws[tid] = 1.0f / (1.0f + expf(-s));
    }
    __syncthreads();
    // apply: out[b][o][h][:] = h2f(outi)*scw[o]*sws[:] + x, coalesced rows
    int w4 = tid & 31, og = tid >> 5;
    long base = (((long)b << 21) + (h << 7)) + (w4 << 2);
    float4_t sv = *(const float4_t*)&sws[w4 << 2];
    #pragma unroll
    for (int o = og; o < 128; o += 8) {
        long idx = base + ((long)o << 14);
        ushort4_t hv = *(const ushort4_t*)&outi[idx];
        float4_t ov = (float4_t){h2f(hv[0]), h2f(hv[1]), h2f(hv[2]), h2f(hv[3])};
        float4_t xv = *(const float4_t*)&x[idx];
        float4_t r = ov * scw[o] * sv + xv;
        *(float4_t*)&out[idx] = r;
    }
}

extern "C" void kernel_launch(void* const* d_in, const int* in_sizes, int n_in,
                              void* d_out, int out_size, void* d_ws, size_t ws_size,
                              hipStream_t stream) {
    const float* x       = (const float*)d_in[0];
    const float* experts = (const float*)d_in[1];
    const float* rw1     = (const float*)d_in[2];
    const float* rbn1_g  = (const float*)d_in[3];
    const float* rbn1_b  = (const float*)d_in[4];
    const float* rw2     = (const float*)d_in[5];
    const float* rbn2_g  = (const float*)d_in[6];
    const float* rbn2_b  = (const float*)d_in[7];
    const float* rw3     = (const float*)d_in[8];
    const float* rb3     = (const float*)d_in[9];
    const float* ca_w1   = (const float*)d_in[10];
    const float* ca_bn1g = (const float*)d_in[11];
    const float* ca_bn1b = (const float*)d_in[12];
    const float* ca_w2   = (const float*)d_in[13];
    const float* ca_bn2g = (const float*)d_in[14];
    const float* ca_bn2b = (const float*)d_in[15];
    const float* sa_w    = (const float*)d_in[16];
    const float* sa_g    = (const float*)d_in[17];
    const float* sa_b    = (const float*)d_in[18];
    float* out = (float*)d_out;
    char* ws = (char*)d_ws;

    ushort_t* xn   = (ushort_t*)(ws);
    ushort_t* w2   = (ushort_t*)(ws + 69222400);
    float*    p    = (float*)(ws + 73940992);
    float*    cp   = (float*)(ws + 73949184);
    float*    cw   = (float*)(ws + 73958400);
    float*    sp   = (float*)(ws + 73966592);
    ushort_t* outi = (ushort_t*)(ws + 76264960);
    float*    st   = (float*)(ws + 143373824);

    hipLaunchKernelGGL(init_kernel, dim3(6445), dim3(256), 0, stream, p, st, sp, xn);
    hipLaunchKernelGGL(transpose_kernel, dim3(4096), dim3(256), 0, stream, x, xn, p, st);
    hipLaunchKernelGGL(wgen_kernel, dim3(128), dim3(256), 0, stream,
                       experts, p, st, rw1, rbn1_g, rbn1_b, rw2, rbn2_g, rbn2_b, rw3, rb3,
                       w2, cp);
    hipLaunchKernelGGL(se_kernel, dim3(1), dim3(256), 0, stream,
                       cp, ca_w1, ca_bn1g, ca_bn1b, ca_w2, ca_bn2g, ca_bn2b, cw);
    hipLaunchKernelGGL(conv_kernel, dim3(2048), dim3(256), 0, stream, xn, w2, cw, outi, sp);
    hipLaunchKernelGGL(sattn_kernel, dim3(2048), dim3(256), 0, stream,
                       sp, sa_w, sa_g, sa_b, cw, x, outi, out);
}